// Round 2
// baseline (250.948 us; speedup 1.0000x reference)
//
#include <hip/hip_runtime.h>

// VectorQuantizer: x [32,64,64,64] f32, emb [512,64] f32 -> out [32,64,64,64] f32
// out[b,:,h,w] = emb[argmin_k dists], where dists must reproduce the numpy/jax
// FLOAT32 computation bit-for-bit:
//   dists[k] = fl( fl(x_sq + e_sq[k]) - fl(2 * dot[k]) )
//   x_sq  = numpy pairwise_sum(x_c^2)    (8 stride-8 accumulators, n=64 path)
//   e_sq  = numpy pairwise_sum(e_c^2)
//   dot   = BLAS sgemm: sequential FMA over c ascending
// The ulp(~64) quantization of fl(x_sq + e_sq[k]) decides ~0.2% of pixels'
// argmins (and creates exact ties -> first-index wins), so higher precision
// is WRONG here — we emulate f32 exactly. _rn intrinsics block fp-contract.

#define KNUM 512
#define CDIM 64

__global__ __launch_bounds__(256) void vq_kernel(
    const float* __restrict__ x,
    const float* __restrict__ emb,
    float* __restrict__ out)
{
    const int tid = threadIdx.x;
    const int p   = blockIdx.x * 256 + tid;          // pixel id, 0..131071
    const int b   = p >> 12;                         // image (H*W = 4096)
    const int hw  = p & 4095;
    const float* xp = x + (((size_t)b * CDIM) << 12) + hw;  // x[b][c][hw], stride 4096

    // e_sq[k] with numpy pairwise-8 semantics, cooperatively (2 KB LDS)
    __shared__ float e_sq[KNUM];
    for (int k = tid; k < KNUM; k += 256) {
        const float* e = emb + k * CDIM;
        float r[8];
        #pragma unroll
        for (int j = 0; j < 8; ++j) r[j] = __fmul_rn(e[j], e[j]);
        #pragma unroll
        for (int i = 8; i < CDIM; i += 8)
            #pragma unroll
            for (int j = 0; j < 8; ++j)
                r[j] = __fadd_rn(r[j], __fmul_rn(e[i + j], e[i + j]));
        e_sq[k] = __fadd_rn(
            __fadd_rn(__fadd_rn(r[0], r[1]), __fadd_rn(r[2], r[3])),
            __fadd_rn(__fadd_rn(r[4], r[5]), __fadd_rn(r[6], r[7])));
    }
    __syncthreads();

    // pixel vector into registers (coalesced: lanes contiguous in hw)
    float xr[CDIM];
    #pragma unroll
    for (int c = 0; c < CDIM; ++c) xr[c] = xp[(size_t)c << 12];

    // x_sq, numpy pairwise-8 semantics
    float xs;
    {
        float r[8];
        #pragma unroll
        for (int j = 0; j < 8; ++j) r[j] = __fmul_rn(xr[j], xr[j]);
        #pragma unroll
        for (int i = 8; i < CDIM; i += 8)
            #pragma unroll
            for (int j = 0; j < 8; ++j)
                r[j] = __fadd_rn(r[j], __fmul_rn(xr[i + j], xr[i + j]));
        xs = __fadd_rn(
            __fadd_rn(__fadd_rn(r[0], r[1]), __fadd_rn(r[2], r[3])),
            __fadd_rn(__fadd_rn(r[4], r[5]), __fadd_rn(r[6], r[7])));
    }

    // argmin over k; 4 rows in flight for ILP (each dot chain is order-pinned)
    float best = 3.4e38f;
    int bidx = 0;
    for (int k = 0; k < KNUM; k += 4) {
        const float* e = emb + k * CDIM;             // uniform address -> s_load
        float d0 = 0.f, d1 = 0.f, d2 = 0.f, d3 = 0.f;
        #pragma unroll
        for (int c = 0; c < CDIM; ++c) {
            const float xc = xr[c];
            d0 = fmaf(xc, e[c          ], d0);       // sequential-c FMA = BLAS order
            d1 = fmaf(xc, e[c + CDIM   ], d1);
            d2 = fmaf(xc, e[c + 2*CDIM ], d2);
            d3 = fmaf(xc, e[c + 3*CDIM ], d3);
        }
        const float s0 = __fsub_rn(__fadd_rn(xs, e_sq[k + 0]), __fmul_rn(2.0f, d0));
        const float s1 = __fsub_rn(__fadd_rn(xs, e_sq[k + 1]), __fmul_rn(2.0f, d1));
        const float s2 = __fsub_rn(__fadd_rn(xs, e_sq[k + 2]), __fmul_rn(2.0f, d2));
        const float s3 = __fsub_rn(__fadd_rn(xs, e_sq[k + 3]), __fmul_rn(2.0f, d3));
        if (s0 < best) { best = s0; bidx = k + 0; }  // strict < => first-min tie-break
        if (s1 < best) { best = s1; bidx = k + 1; }
        if (s2 < best) { best = s2; bidx = k + 2; }
        if (s3 < best) { best = s3; bidx = k + 3; }
    }

    // gather codebook row back to [B,C,H,W] (bit-exact copy of emb row)
    const float* eb = emb + bidx * CDIM;
    float* op = out + (((size_t)b * CDIM) << 12) + hw;
    #pragma unroll
    for (int c = 0; c < CDIM; ++c) op[(size_t)c << 12] = eb[c];
}

extern "C" void kernel_launch(void* const* d_in, const int* in_sizes, int n_in,
                              void* d_out, int out_size, void* d_ws, size_t ws_size,
                              hipStream_t stream)
{
    const float* x   = (const float*)d_in[0];
    const float* emb = (const float*)d_in[1];
    float* out = (float*)d_out;
    const int N = 32 * 64 * 64;  // 131072 pixels
    hipLaunchKernelGGL(vq_kernel, dim3(N / 256), dim3(256), 0, stream, x, emb, out);
}

// Round 3
// 245.223 us; speedup vs baseline: 1.0233x; 1.0233x over previous
//
#include <hip/hip_runtime.h>

// VectorQuantizer: x [32,64,64,64] f32, emb [512,64] f32 -> out [32,64,64,64] f32
// out[b,:,h,w] = emb[argmin_k dists], reproducing numpy FLOAT32 bit semantics:
//   dists[k] = fl( fl(x_sq + e_sq[k]) - fl(2*dot[k]) ), dot = sequential-c FMA,
//   x_sq/e_sq = numpy pairwise-8 sums. Verified absmax==0 in R2.
//
// R3 perf restructure (same per-k arithmetic):
//  - __launch_bounds__(256,4): 128-VGPR budget so xr[64] lives in VGPRs
//    (R2's 40-VGPR build re-loaded x from global every k-group -> 2.3x VALU).
//  - K split across wave-pairs: 256 threads = 128 pixels x 2 k-halves
//    -> 1024 blocks -> 4 waves/SIMD (R2: 2/SIMD, 21% occupancy, 35% stall).
//  - readfirstlane(k-base) keeps emb addresses scalar -> s_load broadcast path
//    (SGPR operand in FMA is free; R2's SGPR_Count=112 confirms this path).
//  - LDS combine: half1 wins only on strict < => global first-occurrence argmin.

#define KNUM 512
#define CDIM 64
#define PPB  128   // pixels per block

__global__ __launch_bounds__(256, 4) void vq_kernel(
    const float* __restrict__ x,
    const float* __restrict__ emb,
    float* __restrict__ out)
{
    const int tid  = threadIdx.x;
    const int lpix = tid & (PPB - 1);                 // pixel-in-block
    const int kh   = __builtin_amdgcn_readfirstlane(tid >> 7);  // k-half, wave-uniform
    const int pix  = blockIdx.x * PPB + lpix;         // 0..131071
    const int b    = pix >> 12;
    const int hw   = pix & 4095;
    const float* xp = x + (((size_t)b * CDIM) << 12) + hw;   // stride 4096 per c

    __shared__ __align__(16) float e_sq[KNUM];
    __shared__ float rbest[2][PPB];
    __shared__ int   ridx [2][PPB];

    // e_sq[k], numpy pairwise-8 semantics, cooperatively (2 rows/thread)
    for (int k = tid; k < KNUM; k += 256) {
        const float* e = emb + k * CDIM;
        float r[8];
        #pragma unroll
        for (int j = 0; j < 8; ++j) r[j] = __fmul_rn(e[j], e[j]);
        #pragma unroll
        for (int i = 8; i < CDIM; i += 8)
            #pragma unroll
            for (int j = 0; j < 8; ++j)
                r[j] = __fadd_rn(r[j], __fmul_rn(e[i + j], e[i + j]));
        e_sq[k] = __fadd_rn(
            __fadd_rn(__fadd_rn(r[0], r[1]), __fadd_rn(r[2], r[3])),
            __fadd_rn(__fadd_rn(r[4], r[5]), __fadd_rn(r[6], r[7])));
    }
    __syncthreads();

    // pixel vector in VGPRs (coalesced: lanes contiguous in hw)
    float xr[CDIM];
    #pragma unroll
    for (int c = 0; c < CDIM; ++c) xr[c] = xp[(size_t)c << 12];

    // x_sq, numpy pairwise-8 semantics
    float xs;
    {
        float r[8];
        #pragma unroll
        for (int j = 0; j < 8; ++j) r[j] = __fmul_rn(xr[j], xr[j]);
        #pragma unroll
        for (int i = 8; i < CDIM; i += 8)
            #pragma unroll
            for (int j = 0; j < 8; ++j)
                r[j] = __fadd_rn(r[j], __fmul_rn(xr[i + j], xr[i + j]));
        xs = __fadd_rn(
            __fadd_rn(__fadd_rn(r[0], r[1]), __fadd_rn(r[2], r[3])),
            __fadd_rn(__fadd_rn(r[4], r[5]), __fadd_rn(r[6], r[7])));
    }

    // this wave-pair scans codes [kh*256, kh*256+256)
    const int k0 = kh << 8;
    float best = 3.4e38f;
    int bidx = k0;
    #pragma unroll 1
    for (int k = k0; k < k0 + 256; k += 4) {
        const float* e = emb + k * CDIM;              // scalar addr -> s_load
        const float4 es4 = *(const float4*)&e_sq[k];  // one ds_read_b128
        float d0 = 0.f, d1 = 0.f, d2 = 0.f, d3 = 0.f;
        #pragma unroll
        for (int c = 0; c < CDIM; ++c) {
            const float xc = xr[c];
            d0 = fmaf(xc, e[c         ], d0);         // sequential-c = BLAS order
            d1 = fmaf(xc, e[c +   CDIM], d1);
            d2 = fmaf(xc, e[c + 2*CDIM], d2);
            d3 = fmaf(xc, e[c + 3*CDIM], d3);
        }
        const float s0 = __fsub_rn(__fadd_rn(xs, es4.x), __fmul_rn(2.0f, d0));
        const float s1 = __fsub_rn(__fadd_rn(xs, es4.y), __fmul_rn(2.0f, d1));
        const float s2 = __fsub_rn(__fadd_rn(xs, es4.z), __fmul_rn(2.0f, d2));
        const float s3 = __fsub_rn(__fadd_rn(xs, es4.w), __fmul_rn(2.0f, d3));
        if (s0 < best) { best = s0; bidx = k + 0; }   // strict < = first-min
        if (s1 < best) { best = s1; bidx = k + 1; }
        if (s2 < best) { best = s2; bidx = k + 2; }
        if (s3 < best) { best = s3; bidx = k + 3; }
    }

    rbest[kh][lpix] = best;
    ridx [kh][lpix] = bidx;
    __syncthreads();

    // combine halves: half1 wins only if strictly smaller (lower k on ties)
    const float b0 = rbest[0][lpix], b1 = rbest[1][lpix];
    const int widx = (b1 < b0) ? ridx[1][lpix] : ridx[0][lpix];

    // gather: each half-thread writes 32 channels (bit-exact emb row copy)
    const float* eb = emb + widx * CDIM + (kh << 5);
    float* op = out + (((size_t)b * CDIM) << 12) + ((size_t)(kh << 5) << 12) + hw;
    #pragma unroll
    for (int c = 0; c < 32; ++c) op[(size_t)c << 12] = eb[c];
}

extern "C" void kernel_launch(void* const* d_in, const int* in_sizes, int n_in,
                              void* d_out, int out_size, void* d_ws, size_t ws_size,
                              hipStream_t stream)
{
    const float* x   = (const float*)d_in[0];
    const float* emb = (const float*)d_in[1];
    float* out = (float*)d_out;
    const int nblocks = (32 * 64 * 64) / PPB;   // 1024
    hipLaunchKernelGGL(vq_kernel, dim3(nblocks), dim3(256), 0, stream, x, emb, out);
}